// Round 1
// baseline (404.986 us; speedup 1.0000x reference)
//
#include <hip/hip_runtime.h>
#include <hip/hip_bf16.h>
#include <float.h>
#include <math.h>

// Problem constants
#define Bn   8
#define Cn   512
#define Tn   4096
#define Kn   512      // codes per sub-codebook
#define SUBn 128      // dims per sub-codebook
#define NROW 32768    // B*T
#define TOTELEM 16777216  // B*C*T

// Tiling
#define BR 64     // rows (t) per block
#define BC 128    // code chunk
#define BK 64     // k chunk
// 256 threads: tc = tid&15 (16 code-groups of 8), tr = tid>>4 (16 row-groups of 4)

struct StageMem { float sA[SUBn][BR]; float sW[BK][BC]; };           // 32KB + 32KB
struct RedMem   { float rv[BR][16]; int ri[BR][16]; int bidx[BR]; float wl[4]; };
union  SMem     { StageMem stage; RedMem red; };

// ---------------- precompute: wT[sub][k][c] and w2[sub][c] ----------------
__global__ __launch_bounds__(256) void vq4_pre(
    const float* __restrict__ w0, const float* __restrict__ w1,
    const float* __restrict__ w2_, const float* __restrict__ w3,
    float* __restrict__ wT, float* __restrict__ w2a)
{
  const int s = blockIdx.x;
  const int tid = threadIdx.x;
  const float* w = (s == 0) ? w0 : (s == 1) ? w1 : (s == 2) ? w2_ : w3;
  float* dst = wT + (size_t)s * SUBn * Kn;

  // transpose 512x128 -> 128x512
  for (int it = 0; it < 64; ++it) {
    int slot = tid + 256 * it;        // 16384 float4 slots: c = slot>>5, kq = slot&31
    int c = slot >> 5, kq = slot & 31;
    float4 v = *(const float4*)(w + (size_t)c * SUBn + 4 * kq);
    dst[(size_t)(4 * kq + 0) * Kn + c] = v.x;
    dst[(size_t)(4 * kq + 1) * Kn + c] = v.y;
    dst[(size_t)(4 * kq + 2) * Kn + c] = v.z;
    dst[(size_t)(4 * kq + 3) * Kn + c] = v.w;
  }
  // squared norms
  for (int it = 0; it < 2; ++it) {
    int c = tid + 256 * it;
    const float* row = w + (size_t)c * SUBn;
    float acc = 0.f;
    #pragma unroll
    for (int k = 0; k < SUBn; k += 4) {
      float4 v = *(const float4*)(row + k);
      acc = fmaf(v.x, v.x, fmaf(v.y, v.y, fmaf(v.z, v.z, fmaf(v.w, v.w, acc))));
    }
    w2a[s * Kn + c] = acc;
  }
}

// ---------------- main: scores + argmin + gather + loss + hist ----------------
__global__ __launch_bounds__(256) void vq4_main(
    const float* __restrict__ x, const float* __restrict__ wT,
    const float* __restrict__ w2a, float* __restrict__ out,
    int* __restrict__ hist, float* __restrict__ lossSum)
{
  __shared__ SMem US;

  const int tb  = blockIdx.x;        // 64 t-blocks
  const int b   = blockIdx.y;        // 8
  const int sub = blockIdx.z;        // 4
  const int t0  = tb * BR;
  const int tid = threadIdx.x;
  const int tc  = tid & 15;          // code group (8 codes: tc*4+j and 64+tc*4+j)
  const int tr  = tid >> 4;          // row group (4 rows: tr*4+i)

  const float* wTs = wT  + (size_t)sub * SUBn * Kn;
  const float* w2s = w2a + (size_t)sub * Kn;
  const float* xb  = x   + (size_t)b * Cn * Tn + (size_t)sub * SUBn * Tn;

  // ---- stage sA: all 128 dims x 64 rows (x is [c][t] => already transposed) ----
  #pragma unroll
  for (int it = 0; it < 8; ++it) {
    int slot = tid + 256 * it;       // 2048: d = slot>>4 (0..127), q = slot&15
    int d = slot >> 4, q = slot & 15;
    float4 v = *(const float4*)(xb + (size_t)d * Tn + t0 + 4 * q);
    *(float4*)&US.stage.sA[d][4 * q] = v;
  }

  float bestV[4];
  int   bestI[4];
  #pragma unroll
  for (int i = 0; i < 4; ++i) { bestV[i] = FLT_MAX; bestI[i] = 0x7fffffff; }

  for (int cc = 0; cc < Kn / BC; ++cc) {
    float acc[4][8];
    #pragma unroll
    for (int i = 0; i < 4; ++i)
      #pragma unroll
      for (int j = 0; j < 8; ++j) acc[i][j] = 0.f;

    for (int kc = 0; kc < SUBn / BK; ++kc) {
      __syncthreads();   // protect prior reads of sW (and first-iter sA writes)
      // stage sW: 64 dims x 128 codes from precomputed wT
      #pragma unroll
      for (int it = 0; it < 8; ++it) {
        int slot = tid + 256 * it;   // 2048: d = slot>>5 (0..63), q = slot&31
        int d = slot >> 5, q = slot & 31;
        float4 v = *(const float4*)(wTs + (size_t)(kc * BK + d) * Kn + cc * BC + 4 * q);
        *(float4*)&US.stage.sW[d][4 * q] = v;
      }
      __syncthreads();

      #pragma unroll 4
      for (int k = 0; k < BK; ++k) {
        float4 av = *(const float4*)&US.stage.sA[kc * BK + k][tr * 4];
        float4 b0 = *(const float4*)&US.stage.sW[k][tc * 4];
        float4 b1 = *(const float4*)&US.stage.sW[k][64 + tc * 4];
        const float a_[4] = {av.x, av.y, av.z, av.w};
        const float b_[8] = {b0.x, b0.y, b0.z, b0.w, b1.x, b1.y, b1.z, b1.w};
        #pragma unroll
        for (int i = 0; i < 4; ++i)
          #pragma unroll
          for (int j = 0; j < 8; ++j)
            acc[i][j] = fmaf(a_[i], b_[j], acc[i][j]);
      }
    }

    // merge chunk into running best (score = ||w||^2 - 2*dot; ascending-c order)
    #pragma unroll
    for (int i = 0; i < 4; ++i) {
      #pragma unroll
      for (int j = 0; j < 8; ++j) {
        int c = cc * BC + ((j < 4) ? (tc * 4 + j) : (64 + tc * 4 + (j - 4)));
        float v = fmaf(-2.f, acc[i][j], w2s[c]);
        if (v < bestV[i]) { bestV[i] = v; bestI[i] = c; }
      }
    }
  }

  // ---- cross-thread argmin reduction ----
  __syncthreads();                   // done with stage memory
  #pragma unroll
  for (int i = 0; i < 4; ++i) {
    US.red.rv[tr * 4 + i][tc] = bestV[i];
    US.red.ri[tr * 4 + i][tc] = bestI[i];
  }
  __syncthreads();
  if (tid < BR) {
    float bv = US.red.rv[tid][0];
    int   bi = US.red.ri[tid][0];
    #pragma unroll
    for (int j = 1; j < 16; ++j) {
      float v = US.red.rv[tid][j];
      int   ii = US.red.ri[tid][j];
      if (v < bv || (v == bv && ii < bi)) { bv = v; bi = ii; }
    }
    US.red.bidx[tid] = bi;
    atomicAdd(&hist[sub * Kn + bi], 1);
  }
  __syncthreads();

  // ---- gather output + fused loss ----
  float lsum = 0.f;
  float* outb = out + (size_t)b * Cn * Tn + (size_t)sub * SUBn * Tn;
  #pragma unroll
  for (int it = 0; it < 8; ++it) {
    int slot = tid + 256 * it;       // 2048: k = slot>>4, q = slot&15
    int k = slot >> 4, q = slot & 15;
    const float* wrow = wTs + (size_t)k * Kn;
    float4 xv = *(const float4*)(xb + (size_t)k * Tn + t0 + 4 * q);
    float4 qv;
    qv.x = wrow[US.red.bidx[4 * q + 0]];
    qv.y = wrow[US.red.bidx[4 * q + 1]];
    qv.z = wrow[US.red.bidx[4 * q + 2]];
    qv.w = wrow[US.red.bidx[4 * q + 3]];
    *(float4*)(outb + (size_t)k * Tn + t0 + 4 * q) = qv;
    float d0 = qv.x - xv.x, d1 = qv.y - xv.y, d2 = qv.z - xv.z, d3 = qv.w - xv.w;
    lsum += d0 * d0 + d1 * d1 + d2 * d2 + d3 * d3;
  }
  // block-reduce loss
  for (int off = 32; off; off >>= 1) lsum += __shfl_down(lsum, off, 64);
  if ((tid & 63) == 0) US.red.wl[tid >> 6] = lsum;
  __syncthreads();
  if (tid == 0)
    atomicAdd(lossSum, US.red.wl[0] + US.red.wl[1] + US.red.wl[2] + US.red.wl[3]);
}

// ---------------- finalize: vq_loss + perplexity ----------------
__global__ __launch_bounds__(256) void vq4_fin(
    const int* __restrict__ hist, const float* __restrict__ lossSum,
    float* __restrict__ out)
{
  const int tid = threadIdx.x;
  float local[4] = {0.f, 0.f, 0.f, 0.f};
  #pragma unroll
  for (int it = 0; it < 8; ++it) {
    int slot = tid + 256 * it;       // 2048 = 4 x 512
    int s = slot >> 9;
    float p = (float)hist[slot] * (1.0f / 32768.0f);
    local[s] += -p * logf(p + 1e-10f);
  }
  __shared__ float red[4][4];
  int lane = tid & 63, wv = tid >> 6;
  #pragma unroll
  for (int s = 0; s < 4; ++s) {
    float v = local[s];
    for (int off = 32; off; off >>= 1) v += __shfl_down(v, off, 64);
    if (lane == 0) red[s][wv] = v;
  }
  __syncthreads();
  if (tid == 0) {
    float loss = 1.25f * lossSum[0] * (1.0f / (float)TOTELEM);
    float perp = 0.f;
    #pragma unroll
    for (int s = 0; s < 4; ++s)
      perp += expf(red[s][0] + red[s][1] + red[s][2] + red[s][3]);
    out[TOTELEM]     = loss;
    out[TOTELEM + 1] = perp;
  }
}

extern "C" void kernel_launch(void* const* d_in, const int* in_sizes, int n_in,
                              void* d_out, int out_size, void* d_ws, size_t ws_size,
                              hipStream_t stream) {
  const float* x  = (const float*)d_in[0];
  const float* w1 = (const float*)d_in[1];
  const float* w2 = (const float*)d_in[2];
  const float* w3 = (const float*)d_in[3];
  const float* w4 = (const float*)d_in[4];
  float* out = (float*)d_out;

  char* ws = (char*)d_ws;
  float* lossSum = (float*)ws;                    // 16 B (padded)
  int*   hist    = (int*)(ws + 16);               // 4*512*4 = 8192 B
  float* w2a     = (float*)(ws + 16 + 8192);      // 8192 B
  float* wT      = (float*)(ws + 16 + 16384);     // 4*128*512*4 = 1 MiB

  // zero accumulators (hist + lossSum) every call — ws is not re-poisoned
  hipMemsetAsync(d_ws, 0, 16 + 8192, stream);

  vq4_pre<<<dim3(4), dim3(256), 0, stream>>>(w1, w2, w3, w4, wT, w2a);
  vq4_main<<<dim3(Tn / BR, Bn, 4), dim3(256), 0, stream>>>(x, wT, w2a, out, hist, lossSum);
  vq4_fin<<<dim3(1), dim3(256), 0, stream>>>(hist, lossSum, out);
}

// Round 2
// 202.008 us; speedup vs baseline: 2.0048x; 2.0048x over previous
//
#include <hip/hip_runtime.h>
#include <hip/hip_bf16.h>
#include <float.h>
#include <math.h>

// Problem constants
#define Bn   8
#define Cn   512
#define Tn   4096
#define Kn   512      // codes per sub-codebook
#define SUBn 128      // dims per sub-codebook
#define TOTELEM 16777216  // B*C*T

typedef __attribute__((ext_vector_type(8))) short bf16x8;   // 8 bf16 = 4 VGPRs
typedef __attribute__((ext_vector_type(4))) float f32x4;    // MFMA acc

static __device__ inline unsigned int pack2(float a, float b) {
  union { __hip_bfloat162 h; unsigned int u; } cv;
  cv.h = __float22bfloat162_rn(make_float2(a, b));
  return cv.u;
}

// ---------------- precompute: wPack (bf16, MFMA-B-fragment order) + ||w||^2 ----
// Fragment-block layout: fb = cBlk*16 + ks*4 + g  (cBlk=c>>4, ks=k>>5, g=(k>>3)&3)
// element offset = fb*128 + (c&15)*8 + (k&7)  -> one wave B-load = contiguous 1KB
__global__ __launch_bounds__(256) void vq4_pre(
    const float* __restrict__ w0, const float* __restrict__ w1,
    const float* __restrict__ w2_, const float* __restrict__ w3,
    unsigned short* __restrict__ wPack, float* __restrict__ w2a)
{
  const int s = blockIdx.x;
  const int tid = threadIdx.x;
  const float* w = (s == 0) ? w0 : (s == 1) ? w1 : (s == 2) ? w2_ : w3;
  unsigned short* dst = wPack + (size_t)s * Kn * SUBn;

  for (int it = 0; it < 64; ++it) {
    int idx = tid + 256 * it;        // 16384 float4 cells: c = idx>>5, k4 = (idx&31)*4
    int c = idx >> 5;
    int k4 = (idx & 31) * 4;
    float4 v = *(const float4*)(w + (size_t)c * SUBn + k4);
    int ks = k4 >> 5, g = (k4 >> 3) & 3, kLo = k4 & 7;   // kLo in {0,4}
    int fb = (c >> 4) * 16 + ks * 4 + g;
    int off = fb * 128 + (c & 15) * 8 + kLo;             // ushort elements
    uint2 p;
    p.x = pack2(v.x, v.y);
    p.y = pack2(v.z, v.w);
    *(uint2*)(dst + off) = p;
  }
  // squared norms
  for (int it = 0; it < 2; ++it) {
    int c = tid + 256 * it;
    const float* row = w + (size_t)c * SUBn;
    float acc = 0.f;
    #pragma unroll
    for (int k = 0; k < SUBn; k += 4) {
      float4 v = *(const float4*)(row + k);
      acc = fmaf(v.x, v.x, fmaf(v.y, v.y, fmaf(v.z, v.z, fmaf(v.w, v.w, acc))));
    }
    w2a[s * Kn + c] = acc;
  }
}

// ---------------- main ----------------
// Block: 256 thr (4 waves), tile = 128 t x 128 k, all 512 codes.
// Waves: wm = wid>>1 (64 t each), wn = wid&1 (256 codes each).
__global__ __launch_bounds__(256, 2) void vq4_main(
    const float* __restrict__ x,
    const unsigned short* __restrict__ wPack,
    const float* __restrict__ w2a,
    const float* __restrict__ w0, const float* __restrict__ w1,
    const float* __restrict__ w2_, const float* __restrict__ w3,
    float* __restrict__ out,
    int* __restrict__ hist, float* __restrict__ lossSum)
{
  __shared__ unsigned char tile[32768];   // x-tile bf16 [t 128][k 128], XOR-swizzled
  __shared__ float pV[2][128];
  __shared__ int   pI[2][128];
  __shared__ int   bIdx[128];
  __shared__ float wl[4];
  __shared__ float wl2[4];

  const int tb  = blockIdx.x;      // 32 t-tiles
  const int b   = blockIdx.y;      // 8
  const int sub = blockIdx.z;      // 4
  const int t0  = tb * 128;
  const int tid = threadIdx.x;
  const int wid = tid >> 6, lane = tid & 63;
  const int r16 = lane & 15, g = lane >> 4;

  const float* xb = x + ((size_t)b * Cn + sub * SUBn) * Tn;

  // ---- stage x tile: fp32 -> bf16, transpose to [t][k], swizzle ((t&15)<<4) ----
  float xsq = 0.f;
  #pragma unroll
  for (int it = 0; it < 2; ++it) {
    int cell = tid + 256 * it;                  // 512 cells: (k8 0..15, q 0..31)
    int k8 = ((cell >> 7) << 2) | (cell & 3);   // 4 distinct low-2-bit values/wave
    int q  = (cell >> 2) & 31;
    float La[8][4];
    #pragma unroll
    for (int i = 0; i < 8; ++i) {
      float4 v = *(const float4*)(xb + (size_t)(k8 * 8 + i) * Tn + t0 + 4 * q);
      La[i][0] = v.x; La[i][1] = v.y; La[i][2] = v.z; La[i][3] = v.w;
      xsq += v.x * v.x + v.y * v.y + v.z * v.z + v.w * v.w;
    }
    #pragma unroll
    for (int j = 0; j < 4; ++j) {
      int t = 4 * q + j;
      uint4 pv;
      pv.x = pack2(La[0][j], La[1][j]);
      pv.y = pack2(La[2][j], La[3][j]);
      pv.z = pack2(La[4][j], La[5][j]);
      pv.w = pack2(La[6][j], La[7][j]);
      int waddr = t * 256 + ((k8 * 16) ^ ((t & 15) << 4));
      *(uint4*)(tile + waddr) = pv;
    }
  }
  // block-reduce sum(x^2) into lossSum (== sum ||s||^2 part of the loss)
  #pragma unroll
  for (int off = 32; off; off >>= 1) xsq += __shfl_down(xsq, off, 64);
  if (lane == 0) wl[wid] = xsq;
  __syncthreads();                 // tile ready + wl ready
  if (tid == 0) atomicAdd(lossSum, wl[0] + wl[1] + wl[2] + wl[3]);

  const int wm = wid >> 1, wn = wid & 1;

  // ---- A fragments: persistent in registers (64 t-rows x 128 k per wave) ----
  bf16x8 aF[4][4];
  #pragma unroll
  for (int mf = 0; mf < 4; ++mf)
    #pragma unroll
    for (int ks = 0; ks < 4; ++ks) {
      int t = wm * 64 + mf * 16 + r16;
      int aaddr = t * 256 + (((ks * 4 + g) * 16) ^ (r16 << 4));  // t&15 == r16
      aF[mf][ks] = *(const bf16x8*)(tile + aaddr);
    }

  const unsigned short* wp = wPack + (size_t)sub * Kn * SUBn + lane * 8;
  const float* w2s = w2a + sub * Kn;

  float bestV[4][4];
  int   bestI[4][4];
  #pragma unroll
  for (int mf = 0; mf < 4; ++mf)
    #pragma unroll
    for (int r = 0; r < 4; ++r) { bestV[mf][r] = FLT_MAX; bestI[mf][r] = 0x7fffffff; }

  // ---- GEMM + running argmin over c-chunks of 64 ----
  #pragma unroll
  for (int cc = 0; cc < 4; ++cc) {
    const int cBase = wn * 256 + cc * 64;
    float w2v[4];
    #pragma unroll
    for (int nf = 0; nf < 4; ++nf) w2v[nf] = w2s[cBase + nf * 16 + r16];

    f32x4 acc[4][4];
    #pragma unroll
    for (int mf = 0; mf < 4; ++mf)
      #pragma unroll
      for (int nf = 0; nf < 4; ++nf) acc[mf][nf] = (f32x4){0.f, 0.f, 0.f, 0.f};

    #pragma unroll
    for (int ks = 0; ks < 4; ++ks) {
      bf16x8 bF[4];
      #pragma unroll
      for (int nf = 0; nf < 4; ++nf) {
        int cBlk = (cBase >> 4) + nf;
        bF[nf] = *(const bf16x8*)(wp + (size_t)(cBlk * 4 + ks) * 512);
      }
      #pragma unroll
      for (int mf = 0; mf < 4; ++mf)
        #pragma unroll
        for (int nf = 0; nf < 4; ++nf)
          acc[mf][nf] = __builtin_amdgcn_mfma_f32_16x16x32_bf16(
              aF[mf][ks], bF[nf], acc[mf][nf], 0, 0, 0);
    }

    // merge chunk: score = ||w||^2 - 2*dot; ascending c, strict < (first-min)
    #pragma unroll
    for (int mf = 0; mf < 4; ++mf)
      #pragma unroll
      for (int nf = 0; nf < 4; ++nf) {
        int c = cBase + nf * 16 + r16;
        #pragma unroll
        for (int r = 0; r < 4; ++r) {
          float v = fmaf(-2.f, acc[mf][nf][r], w2v[nf]);
          if (v < bestV[mf][r]) { bestV[mf][r] = v; bestI[mf][r] = c; }
        }
      }
  }

  // ---- argmin butterfly across the 16 lanes sharing a t-row ----
  #pragma unroll
  for (int d = 1; d < 16; d <<= 1) {
    #pragma unroll
    for (int mf = 0; mf < 4; ++mf)
      #pragma unroll
      for (int r = 0; r < 4; ++r) {
        float ov = __shfl_xor(bestV[mf][r], d, 64);
        int   oi = __shfl_xor(bestI[mf][r], d, 64);
        if (ov < bestV[mf][r] ||
            (ov == bestV[mf][r] && oi < bestI[mf][r])) {
          bestV[mf][r] = ov; bestI[mf][r] = oi;
        }
      }
  }
  // stash per-(wn) partial argmins; C/D layout: t = (l>>4)*4 + reg
  if (r16 == 0) {
    #pragma unroll
    for (int mf = 0; mf < 4; ++mf)
      #pragma unroll
      for (int r = 0; r < 4; ++r) {
        int t = wm * 64 + mf * 16 + g * 4 + r;
        pV[wn][t] = bestV[mf][r];
        pI[wn][t] = bestI[mf][r];
      }
  }
  __syncthreads();

  // ---- final merge across the two c-halves + hist + loss ----
  float bsum = 0.f;
  if (tid < 128) {
    float v0 = pV[0][tid], v1 = pV[1][tid];
    int   i0 = pI[0][tid], i1 = pI[1][tid];
    int   pick1 = (v1 < v0);                 // tie -> lower c (half 0)
    float v = pick1 ? v1 : v0;
    int   i = pick1 ? i1 : i0;
    bIdx[tid] = i;
    atomicAdd(&hist[sub * Kn + i], 1);
    bsum = v;
  }
  #pragma unroll
  for (int off = 32; off; off >>= 1) bsum += __shfl_down(bsum, off, 64);
  if (lane == 0) wl2[wid] = bsum;
  __syncthreads();                 // bIdx ready + wl2 ready
  if (tid == 0) atomicAdd(lossSum, wl2[0] + wl2[1]);

  // ---- gather output rows from ORIGINAL fp32 w (exact values) ----
  const float* worig = (sub == 0) ? w0 : (sub == 1) ? w1 : (sub == 2) ? w2_ : w3;
  float* outb = out + ((size_t)b * Cn + sub * SUBn) * Tn;
  {
    int q = tid & 31, kb = tid >> 5;
    int4 bi4 = *(const int4*)&bIdx[4 * q];
    const float* r0 = worig + (size_t)bi4.x * SUBn;
    const float* r1 = worig + (size_t)bi4.y * SUBn;
    const float* r2 = worig + (size_t)bi4.z * SUBn;
    const float* r3 = worig + (size_t)bi4.w * SUBn;
    #pragma unroll
    for (int kk = 0; kk < 4; ++kk) {
      int k4 = kb * 16 + kk * 4;
      float4 L0 = *(const float4*)(r0 + k4);
      float4 L1 = *(const float4*)(r1 + k4);
      float4 L2 = *(const float4*)(r2 + k4);
      float4 L3 = *(const float4*)(r3 + k4);
      float A0[4] = {L0.x, L0.y, L0.z, L0.w};
      float A1[4] = {L1.x, L1.y, L1.z, L1.w};
      float A2[4] = {L2.x, L2.y, L2.z, L2.w};
      float A3[4] = {L3.x, L3.y, L3.z, L3.w};
      #pragma unroll
      for (int i = 0; i < 4; ++i) {
        float4 o = make_float4(A0[i], A1[i], A2[i], A3[i]);
        *(float4*)(outb + (size_t)(k4 + i) * Tn + t0 + 4 * q) = o;
      }
    }
  }
}

// ---------------- finalize: vq_loss + perplexity ----------------
__global__ __launch_bounds__(256) void vq4_fin(
    const int* __restrict__ hist, const float* __restrict__ lossSum,
    float* __restrict__ out)
{
  const int tid = threadIdx.x;
  float local[4] = {0.f, 0.f, 0.f, 0.f};
  #pragma unroll
  for (int it = 0; it < 8; ++it) {
    int slot = tid + 256 * it;       // 2048 = 4 x 512
    int s = slot >> 9;
    float p = (float)hist[slot] * (1.0f / 32768.0f);
    local[s] += -p * logf(p + 1e-10f);
  }
  __shared__ float red[4][4];
  int lane = tid & 63, wv = tid >> 6;
  #pragma unroll
  for (int s = 0; s < 4; ++s) {
    float v = local[s];
    for (int off = 32; off; off >>= 1) v += __shfl_down(v, off, 64);
    if (lane == 0) red[s][wv] = v;
  }
  __syncthreads();
  if (tid == 0) {
    float loss = 1.25f * lossSum[0] * (1.0f / (float)TOTELEM);
    float perp = 0.f;
    #pragma unroll
    for (int s = 0; s < 4; ++s)
      perp += expf(red[s][0] + red[s][1] + red[s][2] + red[s][3]);
    out[TOTELEM]     = loss;
    out[TOTELEM + 1] = perp;
  }
}

extern "C" void kernel_launch(void* const* d_in, const int* in_sizes, int n_in,
                              void* d_out, int out_size, void* d_ws, size_t ws_size,
                              hipStream_t stream) {
  const float* x  = (const float*)d_in[0];
  const float* w1 = (const float*)d_in[1];
  const float* w2 = (const float*)d_in[2];
  const float* w3 = (const float*)d_in[3];
  const float* w4 = (const float*)d_in[4];
  float* out = (float*)d_out;

  char* ws = (char*)d_ws;
  float* lossSum = (float*)ws;                         // 16 B
  int*   hist    = (int*)(ws + 16);                    // 8192 B
  float* w2a     = (float*)(ws + 16 + 8192);           // 8192 B
  unsigned short* wPack = (unsigned short*)(ws + 16 + 16384);  // 512 KiB

  // zero accumulators (hist + lossSum) every call — ws is not re-poisoned
  hipMemsetAsync(d_ws, 0, 16 + 8192, stream);

  vq4_pre<<<dim3(4), dim3(256), 0, stream>>>(w1, w2, w3, w4, wPack, w2a);
  vq4_main<<<dim3(Tn / 128, Bn, 4), dim3(256), 0, stream>>>(
      x, wPack, w2a, w1, w2, w3, w4, out, hist, lossSum);
  vq4_fin<<<dim3(1), dim3(256), 0, stream>>>(hist, lossSum, out);
}

// Round 4
// 179.755 us; speedup vs baseline: 2.2530x; 1.1238x over previous
//
#include <hip/hip_runtime.h>
#include <hip/hip_bf16.h>
#include <float.h>
#include <math.h>

// Problem constants
#define Bn   8
#define Cn   512
#define Tn   4096
#define Kn   512      // codes per sub-codebook
#define SUBn 128      // dims per sub-codebook
#define TOTELEM 16777216  // B*C*T
#define TILES 2       // t-tiles per block (software pipeline depth)

typedef __attribute__((ext_vector_type(8))) short bf16x8;   // 8 bf16 = 4 VGPRs
typedef __attribute__((ext_vector_type(4))) float f32x4;    // MFMA acc
typedef __attribute__((ext_vector_type(4))) float nf4;      // native float4 (nontemporal ok)

// LDS-only barrier: waits ds ops, leaves vmcnt (global prefetch) in flight.
#define BARRIER() asm volatile("s_waitcnt lgkmcnt(0)\ns_barrier" ::: "memory")

static __device__ inline unsigned int pack2(float a, float b) {
  union { __hip_bfloat162 h; unsigned int u; } cv;
  cv.h = __float22bfloat162_rn(make_float2(a, b));
  return cv.u;
}

// ---------------- precompute: wPack (bf16, MFMA-B-fragment order) + ||w||^2 ----
// fb = cBlk*16 + ks*4 + g  (cBlk=c>>4, ks=k>>5, g=(k>>3)&3)
// element offset = fb*128 + (c&15)*8 + (k&7)
__global__ __launch_bounds__(256) void vq4_pre(
    const float* __restrict__ w0, const float* __restrict__ w1,
    const float* __restrict__ w2_, const float* __restrict__ w3,
    unsigned short* __restrict__ wPack, float* __restrict__ w2a)
{
  const int s = blockIdx.x;
  const int tid = threadIdx.x;
  const float* w = (s == 0) ? w0 : (s == 1) ? w1 : (s == 2) ? w2_ : w3;
  unsigned short* dst = wPack + (size_t)s * Kn * SUBn;

  for (int it = 0; it < 64; ++it) {
    int idx = tid + 256 * it;        // 16384 float4 cells
    int c = idx >> 5;
    int k4 = (idx & 31) * 4;
    nf4 v = *(const nf4*)(w + (size_t)c * SUBn + k4);
    int ks = k4 >> 5, g = (k4 >> 3) & 3, kLo = k4 & 7;
    int fb = (c >> 4) * 16 + ks * 4 + g;
    int off = fb * 128 + (c & 15) * 8 + kLo;
    uint2 p;
    p.x = pack2(v.x, v.y);
    p.y = pack2(v.z, v.w);
    *(uint2*)(dst + off) = p;
  }
  for (int it = 0; it < 2; ++it) {
    int c = tid + 256 * it;
    const float* row = w + (size_t)c * SUBn;
    float acc = 0.f;
    #pragma unroll
    for (int k = 0; k < SUBn; k += 4) {
      nf4 v = *(const nf4*)(row + k);
      acc = fmaf(v.x, v.x, fmaf(v.y, v.y, fmaf(v.z, v.z, fmaf(v.w, v.w, acc))));
    }
    w2a[s * Kn + c] = acc;
  }
}

// ---------------- main ----------------
// 512 threads (8 waves = 2 m-waves x 4 n-waves). Tile: 128 t x 128 k, all 512 c.
// Pipeline: prefetch next tile's x into regs before compute of current tile.
__global__ __launch_bounds__(512, 2) void vq4_main(
    const float* __restrict__ x,
    const unsigned short* __restrict__ wPack,
    const float* __restrict__ w2a,
    const float* __restrict__ w0, const float* __restrict__ w1,
    const float* __restrict__ w2_, const float* __restrict__ w3,
    float* __restrict__ out,
    int* __restrict__ hist, float* __restrict__ lossSum)
{
  __shared__ unsigned char tile[32768];   // x-tile bf16 [t 128][k 128], swizzled
  __shared__ float pV[4][128];
  __shared__ int   pI[4][128];
  __shared__ __align__(16) int bIdx[128];
  __shared__ float wl[8];

  const int bx  = blockIdx.x;      // 16 tile-groups
  const int b   = blockIdx.y;      // 8
  const int sub = blockIdx.z;      // 4
  const int tid = threadIdx.x;
  const int wid = tid >> 6, lane = tid & 63;
  const int r16 = lane & 15, g4 = lane >> 4;
  const int wm = wid >> 2, wn = wid & 3;       // wm: t-half, wn: c-quarter

  // stage mapping: bijective tid -> (sk8 0..15, sq 0..31); 4 sk8-low-bits/wave
  const int sq  = (tid >> 2) & 31;
  const int sk8 = ((tid >> 7) << 2) | (tid & 3);
  // gather mapping
  const int gq  = tid & 31;
  const int gkb = tid >> 5;        // 0..15 -> k rows gkb*8 .. +7

  const float* xb = x + ((size_t)b * Cn + sub * SUBn) * Tn;
  const unsigned short* wp = wPack + (size_t)sub * Kn * SUBn + lane * 8;
  const float* w2s = w2a + sub * Kn;
  const float* worig = (sub == 0) ? w0 : (sub == 1) ? w1 : (sub == 2) ? w2_ : w3;
  float* outb = out + ((size_t)b * Cn + sub * SUBn) * Tn;

  float lossAcc = 0.f;

  // ---- prologue: issue tile-0 loads (nontemporal, x is read once) ----
  nf4 P[8];
  {
    const float* src = xb + (size_t)(sk8 * 8) * Tn + (bx * TILES) * 128 + 4 * sq;
    #pragma unroll
    for (int i = 0; i < 8; ++i)
      P[i] = __builtin_nontemporal_load((const nf4*)(src + (size_t)i * Tn));
  }

  for (int itile = 0; itile < TILES; ++itile) {
    const int t0 = (bx * TILES + itile) * 128;

    // ---- cvt: P -> bf16 LDS tile (+ sum x^2) ----
    {
      float xs = 0.f;
      #pragma unroll
      for (int i = 0; i < 8; ++i)
        xs += P[i].x * P[i].x + P[i].y * P[i].y + P[i].z * P[i].z + P[i].w * P[i].w;
      lossAcc += xs;
      #pragma unroll
      for (int j = 0; j < 4; ++j) {
        int t = 4 * sq + j;
        uint4 pv;
        pv.x = pack2(P[0][j], P[1][j]);
        pv.y = pack2(P[2][j], P[3][j]);
        pv.z = pack2(P[4][j], P[5][j]);
        pv.w = pack2(P[6][j], P[7][j]);
        int waddr = t * 256 + ((sk8 * 16) ^ ((t & 15) << 4));
        *(uint4*)(tile + waddr) = pv;
      }
    }
    // ---- issue next tile's loads NOW (in flight through whole compute) ----
    if (itile + 1 < TILES) {
      const float* src = xb + (size_t)(sk8 * 8) * Tn + (t0 + 128) + 4 * sq;
      #pragma unroll
      for (int i = 0; i < 8; ++i)
        P[i] = __builtin_nontemporal_load((const nf4*)(src + (size_t)i * Tn));
    }
    BARRIER();                      // tile ready (lgkm only; vmcnt stays)

    // ---- A fragments from LDS (64 t x 128 k per wave) ----
    bf16x8 aF[4][4];
    #pragma unroll
    for (int mf = 0; mf < 4; ++mf)
      #pragma unroll
      for (int ks = 0; ks < 4; ++ks) {
        int t = wm * 64 + mf * 16 + r16;
        int aaddr = t * 256 + ((((ks * 4 + g4) * 16)) ^ (r16 << 4));
        aF[mf][ks] = *(const bf16x8*)(tile + aaddr);
      }

    float bestV[4][4];
    int   bestI[4][4];
    #pragma unroll
    for (int mf = 0; mf < 4; ++mf)
      #pragma unroll
      for (int r = 0; r < 4; ++r) { bestV[mf][r] = FLT_MAX; bestI[mf][r] = 0x7fffffff; }

    // ---- GEMM over this wave's 128 codes (2 chunks of 64) + running argmin ----
    #pragma unroll
    for (int cc = 0; cc < 2; ++cc) {
      const int cBase = wn * 128 + cc * 64;
      float w2v[4];
      #pragma unroll
      for (int nf = 0; nf < 4; ++nf) w2v[nf] = w2s[cBase + nf * 16 + r16];

      f32x4 acc[4][4];
      #pragma unroll
      for (int mf = 0; mf < 4; ++mf)
        #pragma unroll
        for (int nf = 0; nf < 4; ++nf) acc[mf][nf] = (f32x4){0.f, 0.f, 0.f, 0.f};

      #pragma unroll
      for (int ks = 0; ks < 4; ++ks) {
        bf16x8 bF[4];
        #pragma unroll
        for (int nf = 0; nf < 4; ++nf) {
          int cBlk = (cBase >> 4) + nf;
          bF[nf] = *(const bf16x8*)(wp + (size_t)(cBlk * 4 + ks) * 512);
        }
        #pragma unroll
        for (int mf = 0; mf < 4; ++mf)
          #pragma unroll
          for (int nf = 0; nf < 4; ++nf)
            acc[mf][nf] = __builtin_amdgcn_mfma_f32_16x16x32_bf16(
                aF[mf][ks], bF[nf], acc[mf][nf], 0, 0, 0);
      }

      #pragma unroll
      for (int mf = 0; mf < 4; ++mf)
        #pragma unroll
        for (int nf = 0; nf < 4; ++nf) {
          int c = cBase + nf * 16 + r16;
          #pragma unroll
          for (int r = 0; r < 4; ++r) {
            float v = fmaf(-2.f, acc[mf][nf][r], w2v[nf]);
            if (v < bestV[mf][r]) { bestV[mf][r] = v; bestI[mf][r] = c; }
          }
        }
    }

    // ---- argmin butterfly across 16 lanes sharing a t-row ----
    #pragma unroll
    for (int d = 1; d < 16; d <<= 1) {
      #pragma unroll
      for (int mf = 0; mf < 4; ++mf)
        #pragma unroll
        for (int r = 0; r < 4; ++r) {
          float ov = __shfl_xor(bestV[mf][r], d, 64);
          int   oi = __shfl_xor(bestI[mf][r], d, 64);
          if (ov < bestV[mf][r] ||
              (ov == bestV[mf][r] && oi < bestI[mf][r])) {
            bestV[mf][r] = ov; bestI[mf][r] = oi;
          }
        }
    }
    if (r16 == 0) {
      #pragma unroll
      for (int mf = 0; mf < 4; ++mf)
        #pragma unroll
        for (int r = 0; r < 4; ++r) {
          int t = wm * 64 + mf * 16 + g4 * 4 + r;   // C/D: row=(l>>4)*4+reg
          pV[wn][t] = bestV[mf][r];
          pI[wn][t] = bestI[mf][r];
        }
    }
    BARRIER();

    // ---- merge the 4 c-quarters + hist + loss ----
    if (tid < 128) {
      float bv = pV[0][tid];
      int   bi = pI[0][tid];
      #pragma unroll
      for (int h = 1; h < 4; ++h) {
        float v = pV[h][tid];
        int   ii = pI[h][tid];
        if (v < bv || (v == bv && ii < bi)) { bv = v; bi = ii; }
      }
      bIdx[tid] = bi;
      atomicAdd(&hist[sub * Kn + bi], 1);
      lossAcc += bv;                 // sum of best (||w||^2 - 2 s.w)
    }
    BARRIER();                       // bIdx ready

    // ---- gather output rows from original fp32 w; nontemporal stores ----
    {
      int4 bi4 = *(const int4*)&bIdx[4 * gq];
      const float* r0 = worig + (size_t)bi4.x * SUBn;
      const float* r1 = worig + (size_t)bi4.y * SUBn;
      const float* r2 = worig + (size_t)bi4.z * SUBn;
      const float* r3 = worig + (size_t)bi4.w * SUBn;
      #pragma unroll
      for (int kk = 0; kk < 2; ++kk) {
        int k4 = gkb * 8 + kk * 4;
        nf4 L0 = *(const nf4*)(r0 + k4);
        nf4 L1 = *(const nf4*)(r1 + k4);
        nf4 L2 = *(const nf4*)(r2 + k4);
        nf4 L3 = *(const nf4*)(r3 + k4);
        #pragma unroll
        for (int i = 0; i < 4; ++i) {
          nf4 o = {L0[i], L1[i], L2[i], L3[i]};
          __builtin_nontemporal_store(o,
              (nf4*)(outb + (size_t)(k4 + i) * Tn + t0 + 4 * gq));
        }
      }
    }
    // no barrier needed: next cvt writes tile[] (not read here); bIdx rewrite
    // is 2 barriers away.
  }

  // ---- block loss reduction -> one atomic ----
  #pragma unroll
  for (int off = 32; off; off >>= 1) lossAcc += __shfl_down(lossAcc, off, 64);
  if (lane == 0) wl[wid] = lossAcc;
  BARRIER();
  if (tid == 0) {
    float s = 0.f;
    #pragma unroll
    for (int w = 0; w < 8; ++w) s += wl[w];
    atomicAdd(lossSum, s);
  }
}

// ---------------- finalize: vq_loss + perplexity ----------------
__global__ __launch_bounds__(256) void vq4_fin(
    const int* __restrict__ hist, const float* __restrict__ lossSum,
    float* __restrict__ out)
{
  const int tid = threadIdx.x;
  float local[4] = {0.f, 0.f, 0.f, 0.f};
  #pragma unroll
  for (int it = 0; it < 8; ++it) {
    int slot = tid + 256 * it;       // 2048 = 4 x 512
    int s = slot >> 9;
    float p = (float)hist[slot] * (1.0f / 32768.0f);
    local[s] += -p * logf(p + 1e-10f);
  }
  __shared__ float red[4][4];
  int lane = tid & 63, wv = tid >> 6;
  #pragma unroll
  for (int s = 0; s < 4; ++s) {
    float v = local[s];
    for (int off = 32; off; off >>= 1) v += __shfl_down(v, off, 64);
    if (lane == 0) red[s][wv] = v;
  }
  __syncthreads();
  if (tid == 0) {
    float loss = 1.25f * lossSum[0] * (1.0f / (float)TOTELEM);
    float perp = 0.f;
    #pragma unroll
    for (int s = 0; s < 4; ++s)
      perp += expf(red[s][0] + red[s][1] + red[s][2] + red[s][3]);
    out[TOTELEM]     = loss;
    out[TOTELEM + 1] = perp;
  }
}

extern "C" void kernel_launch(void* const* d_in, const int* in_sizes, int n_in,
                              void* d_out, int out_size, void* d_ws, size_t ws_size,
                              hipStream_t stream) {
  const float* x  = (const float*)d_in[0];
  const float* w1 = (const float*)d_in[1];
  const float* w2 = (const float*)d_in[2];
  const float* w3 = (const float*)d_in[3];
  const float* w4 = (const float*)d_in[4];
  float* out = (float*)d_out;

  char* ws = (char*)d_ws;
  float* lossSum = (float*)ws;                         // 16 B
  int*   hist    = (int*)(ws + 16);                    // 8192 B
  float* w2a     = (float*)(ws + 16 + 8192);           // 8192 B
  unsigned short* wPack = (unsigned short*)(ws + 16 + 16384);  // 512 KiB

  // zero accumulators (hist + lossSum) every call — ws is not re-poisoned
  (void)hipMemsetAsync(d_ws, 0, 16 + 8192, stream);

  vq4_pre<<<dim3(4), dim3(256), 0, stream>>>(w1, w2, w3, w4, wPack, w2a);
  vq4_main<<<dim3(Tn / 128 / TILES, Bn, 4), dim3(512), 0, stream>>>(
      x, wPack, w2a, w1, w2, w3, w4, out, hist, lossSum);
  vq4_fin<<<dim3(1), dim3(256), 0, stream>>>(hist, lossSum, out);
}